// Round 1
// baseline (790.106 us; speedup 1.0000x reference)
//
#include <hip/hip_runtime.h>
#include <cstdint>
#include <cstddef>

#define DEV __device__ __forceinline__

typedef unsigned short u16;
typedef _Float16 f16x8 __attribute__((ext_vector_type(8)));
typedef float f32x4 __attribute__((ext_vector_type(4)));

static constexpr int NB  = 16;     // batch samples
static constexpr int T   = 2048;   // tokens per sample (C*S = 32*64)
static constexpr int D   = 512;
static constexpr int DFF = 2048;
static constexpr int NE  = 8;
static constexpr int FEAT = 3 * D; // 1536

DEV u16 f2h(float f) {
  _Float16 h = (_Float16)f;
  union { _Float16 h; u16 u; } cv; cv.h = h; return cv.u;
}

DEV float gelu_tanh(float x) {
  float u = 0.7978845608028654f * (x + 0.044715f * x * x * x);
  return 0.5f * x * (1.0f + tanhf(u));
}

// ---------------- routing path (fp32) ----------------

// partial sums over 128-row chunks: part[0..16*16*512) = baseline, next = attnres
__global__ void k_part(const float* __restrict__ base, const float* __restrict__ attn,
                       float* __restrict__ part) {
  const int b = blockIdx.x >> 4, ch = blockIdx.x & 15;
  const int d = threadIdx.x;
  const size_t o = ((size_t)b * T + (size_t)ch * 128) * D + d;
  const float* pb = base + o;
  const float* pa = attn + o;
  float sb = 0.f, sa = 0.f;
  for (int r = 0; r < 128; ++r) { sb += pb[(size_t)r * D]; sa += pa[(size_t)r * D]; }
  part[(b * 16 + ch) * D + d] = sb;
  part[NB * 16 * D + (b * 16 + ch) * D + d] = sa;
}

__global__ void k_feat(const float* __restrict__ part, float* __restrict__ feat) {
  const int b = blockIdx.x, d = threadIdx.x;
  float sb = 0.f, sa = 0.f;
  for (int ch = 0; ch < 16; ++ch) {
    sb += part[(b * 16 + ch) * D + d];
    sa += part[NB * 16 * D + (b * 16 + ch) * D + d];
  }
  sb *= (1.0f / 2048.0f); sa *= (1.0f / 2048.0f);
  feat[b * FEAT + d] = sb;
  feat[b * FEAT + D + d] = sa;
  feat[b * FEAT + 2 * D + d] = sa - sb;
}

// one wave per (router, sample): logits -> argmax + softmax gate
__global__ void k_route(const float* __restrict__ feat,
                        const float* __restrict__ rw0, const float* __restrict__ rb0,
                        const float* __restrict__ rw1, const float* __restrict__ rb1,
                        int* __restrict__ idx, float* __restrict__ gate) {
  const int r = blockIdx.x >> 4, b = blockIdx.x & 15;
  const float* rw = (r == 0) ? rw0 : rw1;
  const float* rb = (r == 0) ? rb0 : rb1;
  const int l = threadIdx.x;
  float p[8];
#pragma unroll
  for (int e = 0; e < 8; ++e) p[e] = 0.f;
  const float* f = feat + b * FEAT;
  for (int k = l; k < FEAT; k += 64) {
    const float fv = f[k];
#pragma unroll
    for (int e = 0; e < 8; ++e) p[e] += fv * rw[e * FEAT + k];
  }
#pragma unroll
  for (int off = 32; off >= 1; off >>= 1) {
#pragma unroll
    for (int e = 0; e < 8; ++e) p[e] += __shfl_xor(p[e], off);
  }
  if (l == 0) {
    float best = -1e30f; int bi = 0;
    float lg[8];
#pragma unroll
    for (int e = 0; e < 8; ++e) {
      lg[e] = p[e] + rb[e];
      if (lg[e] > best) { best = lg[e]; bi = e; }
    }
    float s = 0.f;
#pragma unroll
    for (int e = 0; e < 8; ++e) s += expf(lg[e] - best);
    idx[r * 16 + b] = bi;
    gate[r * 16 + b] = 1.0f / s;   // softmax prob of the argmax logit
  }
}

// bias_total[b][d] = shared_b2[d] + g_spa*spa_b2[ia][d] + g_spe*spe_b2[ie][d]
__global__ void k_btot(const float* __restrict__ b2s, const float* __restrict__ b2a,
                       const float* __restrict__ b2e, const int* __restrict__ idx,
                       const float* __restrict__ gate, float* __restrict__ btot) {
  const int b = blockIdx.x, d = threadIdx.x;
  const int ia = idx[b], ie = idx[16 + b];
  const float ga = gate[b], ge = gate[16 + b];
  btot[b * D + d] = b2s[d] + ga * b2a[ia * D + d] + ge * b2e[ie * D + d];
}

// ---------------- fp32 -> fp16 cast ----------------
__global__ void k_cast(const float* __restrict__ s, u16* __restrict__ d, long n) {
  const long i = ((long)blockIdx.x * blockDim.x + threadIdx.x) * 4;
  if (i >= n) return;
  const float4 v = *(const float4*)(s + i);
  const unsigned int lo = (unsigned int)f2h(v.x) | ((unsigned int)f2h(v.y) << 16);
  const unsigned int hi = (unsigned int)f2h(v.z) | ((unsigned int)f2h(v.w) << 16);
  *(uint2*)(d + i) = make_uint2(lo, hi);
}

// ---------------- GEMM core (m97 structure: 128x128 tile, BK=64, 4 waves) ----------------

DEV void ld_lds16(const void* g, void* l) {
  __builtin_amdgcn_global_load_lds((const __attribute__((address_space(1))) void*)g,
                                   (__attribute__((address_space(3))) void*)l, 16, 0, 0);
}

// A: [128 x K] rows at lda, B^T: [128 x K] rows at ldb (both K-major), K = NKT*64
template <int NKT>
DEV void gemm_core(const u16* __restrict__ Ab, int lda, const u16* __restrict__ Bb, int ldb,
                   u16* As, u16* Bs, f32x4 (&acc)[4][4]) {
  const int tid = threadIdx.x;
  const int lane = tid & 63, wid = tid >> 6;
  const int wr = wid >> 1, wc = wid & 1;
  const int arow = wr * 64 + (lane & 15);
  const int brow = wc * 64 + (lane & 15);
  const int koff = (lane >> 4) * 8;
  const int srow = tid >> 3;          // 0..31
  const int scol = (tid & 7) * 8;     // element offset (16B chunks)
  const u16* ga = Ab + (size_t)srow * lda + scol;
  const u16* gb = Bb + (size_t)srow * ldb + scol;
  u16* lA = As + wid * 512;           // wave-uniform LDS slice
  u16* lB = Bs + wid * 512;

  for (int kt = 0; kt < NKT; ++kt) {
    const int k0 = kt * 64;
#pragma unroll
    for (int i = 0; i < 4; ++i)
      ld_lds16(ga + (size_t)(i * 32) * lda + k0, lA + i * 2048);
#pragma unroll
    for (int i = 0; i < 4; ++i)
      ld_lds16(gb + (size_t)(i * 32) * ldb + k0, lB + i * 2048);
    __syncthreads();   // drains vmcnt -> LDS tiles valid
#pragma unroll
    for (int kk = 0; kk < 2; ++kk) {
      f16x8 av[4], bv[4];
#pragma unroll
      for (int m = 0; m < 4; ++m)
        av[m] = *(const f16x8*)(As + (arow + m * 16) * 64 + kk * 32 + koff);
#pragma unroll
      for (int n = 0; n < 4; ++n)
        bv[n] = *(const f16x8*)(Bs + (brow + n * 16) * 64 + kk * 32 + koff);
#pragma unroll
      for (int m = 0; m < 4; ++m) {
#pragma unroll
        for (int n = 0; n < 4; ++n)
          acc[m][n] = __builtin_amdgcn_mfma_f32_16x16x32_f16(av[m], bv[n], acc[m][n], 0, 0, 0);
      }
    }
    __syncthreads();
  }
}

// GEMM1: h[b] = gate * gelu(x[b] @ W1^T + b1)   (M=2048, N=2048, K=512)
template <int BANK>
__global__ __launch_bounds__(256, 2) void k_ffn1(
    const u16* __restrict__ xh, const u16* __restrict__ w1, const float* __restrict__ b1,
    const int* __restrict__ idx, const float* __restrict__ gate, u16* __restrict__ h) {
  __shared__ alignas(16) u16 As[128 * 64];
  __shared__ alignas(16) u16 Bs[128 * 64];
  const int b = blockIdx.y;
  const int mt = blockIdx.x >> 4;
  const int nt = blockIdx.x & 15;
  const int e = (BANK == 0) ? 0 : idx[(BANK - 1) * 16 + b];
  const float g = (BANK == 0) ? 1.0f : gate[(BANK - 1) * 16 + b];
  const u16* Ab = xh + ((size_t)b * T + (size_t)mt * 128) * D;
  const u16* Bb = w1 + (size_t)e * DFF * D + (size_t)nt * 128 * D;
  const float* bb = b1 + (size_t)e * DFF;

  f32x4 acc[4][4];
#pragma unroll
  for (int m = 0; m < 4; ++m)
#pragma unroll
    for (int n = 0; n < 4; ++n)
#pragma unroll
      for (int r = 0; r < 4; ++r) acc[m][n][r] = 0.f;

  gemm_core<8>(Ab, D, Bb, D, As, Bs, acc);

  const int lane = threadIdx.x & 63, wid = threadIdx.x >> 6;
  const int wr = wid >> 1, wc = wid & 1;
  const int rr = (lane >> 4) << 2, cc = lane & 15;
  u16* hb = h + (size_t)b * T * DFF;
#pragma unroll
  for (int mi = 0; mi < 4; ++mi) {
    const int row = mt * 128 + wr * 64 + mi * 16 + rr;
#pragma unroll
    for (int ni = 0; ni < 4; ++ni) {
      const int col = nt * 128 + wc * 64 + ni * 16 + cc;
      const float bv = bb[col];
      const f32x4 a = acc[mi][ni];
#pragma unroll
      for (int r = 0; r < 4; ++r) {
        const float v = gelu_tanh(a[r] + bv) * g;
        hb[(size_t)(row + r) * DFF + col] = f2h(v);
      }
    }
  }
}

// GEMM2: out[b] (+)= h[b] @ W2^T  (+ bias_total on BANK 0)  (M=2048, N=512, K=2048)
template <int BANK>
__global__ __launch_bounds__(256, 2) void k_ffn2(
    const u16* __restrict__ h, const u16* __restrict__ w2, const float* __restrict__ btot,
    const int* __restrict__ idx, float* __restrict__ out) {
  __shared__ alignas(16) u16 As[128 * 64];
  __shared__ alignas(16) u16 Bs[128 * 64];
  const int b = blockIdx.y;
  const int mt = blockIdx.x >> 2;
  const int nt = blockIdx.x & 3;
  const int e = (BANK == 0) ? 0 : idx[(BANK - 1) * 16 + b];
  const u16* Ab = h + ((size_t)b * T + (size_t)mt * 128) * DFF;
  const u16* Bb = w2 + (size_t)e * D * DFF + (size_t)nt * 128 * DFF;

  f32x4 acc[4][4];
#pragma unroll
  for (int m = 0; m < 4; ++m)
#pragma unroll
    for (int n = 0; n < 4; ++n)
#pragma unroll
      for (int r = 0; r < 4; ++r) acc[m][n][r] = 0.f;

  gemm_core<32>(Ab, DFF, Bb, DFF, As, Bs, acc);

  const int lane = threadIdx.x & 63, wid = threadIdx.x >> 6;
  const int wr = wid >> 1, wc = wid & 1;
  const int rr = (lane >> 4) << 2, cc = lane & 15;
  float* ob = out + (size_t)b * T * D;
  const float* bt = btot + b * D;
#pragma unroll
  for (int mi = 0; mi < 4; ++mi) {
    const int row = mt * 128 + wr * 64 + mi * 16 + rr;
#pragma unroll
    for (int ni = 0; ni < 4; ++ni) {
      const int col = nt * 128 + wc * 64 + ni * 16 + cc;
      const f32x4 a = acc[mi][ni];
#pragma unroll
      for (int r = 0; r < 4; ++r) {
        const size_t oi = (size_t)(row + r) * D + col;
        if (BANK == 0) ob[oi] = a[r] + bt[col];
        else           ob[oi] += a[r];
      }
    }
  }
}

// ---------------- launch ----------------

extern "C" void kernel_launch(void* const* d_in, const int* in_sizes, int n_in,
                              void* d_out, int out_size, void* d_ws, size_t ws_size,
                              hipStream_t stream) {
  (void)in_sizes; (void)n_in; (void)out_size; (void)ws_size;
  const float* x    = (const float*)d_in[0];
  const float* base = (const float*)d_in[1];
  const float* attn = (const float*)d_in[2];
  const float* sw1  = (const float*)d_in[3];
  const float* sb1  = (const float*)d_in[4];
  const float* sw2  = (const float*)d_in[5];
  const float* sb2  = (const float*)d_in[6];
  const float* arw  = (const float*)d_in[7];
  const float* arb  = (const float*)d_in[8];
  const float* erw  = (const float*)d_in[9];
  const float* erb  = (const float*)d_in[10];
  const float* aw1  = (const float*)d_in[11];
  const float* ab1  = (const float*)d_in[12];
  const float* aw2  = (const float*)d_in[13];
  const float* ab2  = (const float*)d_in[14];
  const float* ew1  = (const float*)d_in[15];
  const float* eb1  = (const float*)d_in[16];
  const float* ew2  = (const float*)d_in[17];
  const float* eb2  = (const float*)d_in[18];
  float* out = (float*)d_out;

  char* w = (char*)d_ws;
  u16* xh   = (u16*)w;  w += (size_t)NB * T * D * 2;        // 33.5 MB
  u16* hbuf = (u16*)w;  w += (size_t)NB * T * DFF * 2;      // 134 MB (one bank at a time)
  u16* w1s  = (u16*)w;  w += (size_t)DFF * D * 2;
  u16* w2s  = (u16*)w;  w += (size_t)D * DFF * 2;
  u16* w1a  = (u16*)w;  w += (size_t)NE * DFF * D * 2;
  u16* w2a  = (u16*)w;  w += (size_t)NE * D * DFF * 2;
  u16* w1e  = (u16*)w;  w += (size_t)NE * DFF * D * 2;
  u16* w2e  = (u16*)w;  w += (size_t)NE * D * DFF * 2;
  float* part = (float*)w; w += (size_t)2 * NB * 16 * D * 4;
  float* feat = (float*)w; w += (size_t)NB * FEAT * 4;
  int*   idx  = (int*)w;   w += 32 * 4;
  float* gate = (float*)w; w += 32 * 4;
  float* btot = (float*)w; w += (size_t)NB * D * 4;

  // routing path
  k_part<<<dim3(256), dim3(512), 0, stream>>>(base, attn, part);
  k_feat<<<dim3(16), dim3(512), 0, stream>>>(part, feat);
  k_route<<<dim3(32), dim3(64), 0, stream>>>(feat, arw, arb, erw, erb, idx, gate);
  k_btot<<<dim3(16), dim3(512), 0, stream>>>(sb2, ab2, eb2, idx, gate, btot);

  // fp32 -> fp16 casts (all sizes divisible by 1024)
  {
    long n;
    n = (long)NB * T * D;      k_cast<<<(unsigned)(n / 1024), 256, 0, stream>>>(x,   xh,  n);
    n = (long)DFF * D;         k_cast<<<(unsigned)(n / 1024), 256, 0, stream>>>(sw1, w1s, n);
    n = (long)D * DFF;         k_cast<<<(unsigned)(n / 1024), 256, 0, stream>>>(sw2, w2s, n);
    n = (long)NE * DFF * D;    k_cast<<<(unsigned)(n / 1024), 256, 0, stream>>>(aw1, w1a, n);
    n = (long)NE * D * DFF;    k_cast<<<(unsigned)(n / 1024), 256, 0, stream>>>(aw2, w2a, n);
    n = (long)NE * DFF * D;    k_cast<<<(unsigned)(n / 1024), 256, 0, stream>>>(ew1, w1e, n);
    n = (long)NE * D * DFF;    k_cast<<<(unsigned)(n / 1024), 256, 0, stream>>>(ew2, w2e, n);
  }

  // three bank passes: shared, spa, spe
  const dim3 g1(256, 16), g2(64, 16), blk(256);
  k_ffn1<0><<<g1, blk, 0, stream>>>(xh, w1s, sb1, idx, gate, hbuf);
  k_ffn2<0><<<g2, blk, 0, stream>>>(hbuf, w2s, btot, idx, out);
  k_ffn1<1><<<g1, blk, 0, stream>>>(xh, w1a, ab1, idx, gate, hbuf);
  k_ffn2<1><<<g2, blk, 0, stream>>>(hbuf, w2a, btot, idx, out);
  k_ffn1<2><<<g1, blk, 0, stream>>>(xh, w1e, eb1, idx, gate, hbuf);
  k_ffn2<2><<<g2, blk, 0, stream>>>(hbuf, w2e, btot, idx, out);
}

// Round 2
// 737.089 us; speedup vs baseline: 1.0719x; 1.0719x over previous
//
#include <hip/hip_runtime.h>
#include <cstdint>
#include <cstddef>

#define DEV __device__ __forceinline__

typedef unsigned short u16;
typedef _Float16 f16x8 __attribute__((ext_vector_type(8)));
typedef float f32x4 __attribute__((ext_vector_type(4)));

static constexpr int NB  = 16;     // batch samples
static constexpr int T   = 2048;   // tokens per sample (C*S = 32*64)
static constexpr int D   = 512;
static constexpr int DFF = 2048;
static constexpr int NE  = 8;
static constexpr int FEAT = 3 * D; // 1536

#define MFMA16 __builtin_amdgcn_mfma_f32_16x16x32_f16

DEV u16 f2h(float f) {
  _Float16 h = (_Float16)f;
  union { _Float16 h; u16 u; } cv; cv.h = h; return cv.u;
}

// gelu(x) = x * sigmoid(2u), u = 0.7978845608*(x + 0.044715 x^3)
DEV float gelu_fast(float x) {
  const float t = x * x;
  const float p = x * fmaf(t, -0.07135481627f, -1.59576912161f);  // -2u
  return __fdividef(x, 1.0f + __expf(p));
}

// ---------------- routing path (fp32) ----------------

__global__ void k_part(const float* __restrict__ base, const float* __restrict__ attn,
                       float* __restrict__ part) {
  const int b = blockIdx.x >> 4, ch = blockIdx.x & 15;
  const int d = threadIdx.x;
  const size_t o = ((size_t)b * T + (size_t)ch * 128) * D + d;
  const float* pb = base + o;
  const float* pa = attn + o;
  float sb = 0.f, sa = 0.f;
  for (int r = 0; r < 128; ++r) { sb += pb[(size_t)r * D]; sa += pa[(size_t)r * D]; }
  part[(b * 16 + ch) * D + d] = sb;
  part[NB * 16 * D + (b * 16 + ch) * D + d] = sa;
}

__global__ void k_feat(const float* __restrict__ part, float* __restrict__ feat) {
  const int b = blockIdx.x, d = threadIdx.x;
  float sb = 0.f, sa = 0.f;
  for (int ch = 0; ch < 16; ++ch) {
    sb += part[(b * 16 + ch) * D + d];
    sa += part[NB * 16 * D + (b * 16 + ch) * D + d];
  }
  sb *= (1.0f / 2048.0f); sa *= (1.0f / 2048.0f);
  feat[b * FEAT + d] = sb;
  feat[b * FEAT + D + d] = sa;
  feat[b * FEAT + 2 * D + d] = sa - sb;
}

__global__ void k_route(const float* __restrict__ feat,
                        const float* __restrict__ rw0, const float* __restrict__ rb0,
                        const float* __restrict__ rw1, const float* __restrict__ rb1,
                        int* __restrict__ idx, float* __restrict__ gate) {
  const int r = blockIdx.x >> 4, b = blockIdx.x & 15;
  const float* rw = (r == 0) ? rw0 : rw1;
  const float* rb = (r == 0) ? rb0 : rb1;
  const int l = threadIdx.x;
  float p[8];
#pragma unroll
  for (int e = 0; e < 8; ++e) p[e] = 0.f;
  const float* f = feat + b * FEAT;
  for (int k = l; k < FEAT; k += 64) {
    const float fv = f[k];
#pragma unroll
    for (int e = 0; e < 8; ++e) p[e] += fv * rw[e * FEAT + k];
  }
#pragma unroll
  for (int off = 32; off >= 1; off >>= 1) {
#pragma unroll
    for (int e = 0; e < 8; ++e) p[e] += __shfl_xor(p[e], off);
  }
  if (l == 0) {
    float best = -1e30f; int bi = 0;
    float lg[8];
#pragma unroll
    for (int e = 0; e < 8; ++e) {
      lg[e] = p[e] + rb[e];
      if (lg[e] > best) { best = lg[e]; bi = e; }
    }
    float s = 0.f;
#pragma unroll
    for (int e = 0; e < 8; ++e) s += expf(lg[e] - best);
    idx[r * 16 + b] = bi;
    gate[r * 16 + b] = 1.0f / s;
  }
}

__global__ void k_btot(const float* __restrict__ b2s, const float* __restrict__ b2a,
                       const float* __restrict__ b2e, const int* __restrict__ idx,
                       const float* __restrict__ gate, float* __restrict__ btot) {
  const int b = blockIdx.x, d = threadIdx.x;
  const int ia = idx[b], ie = idx[16 + b];
  const float ga = gate[b], ge = gate[16 + b];
  btot[b * D + d] = b2s[d] + ga * b2a[ia * D + d] + ge * b2e[ie * D + d];
}

// ---------------- fp32 -> fp16 cast ----------------
__global__ void k_cast(const float* __restrict__ s, u16* __restrict__ d, long n) {
  const long i = ((long)blockIdx.x * blockDim.x + threadIdx.x) * 4;
  if (i >= n) return;
  const float4 v = *(const float4*)(s + i);
  const unsigned int lo = (unsigned int)f2h(v.x) | ((unsigned int)f2h(v.y) << 16);
  const unsigned int hi = (unsigned int)f2h(v.z) | ((unsigned int)f2h(v.w) << 16);
  *(uint2*)(d + i) = make_uint2(lo, hi);
}

// ---------------- 256x256 pipelined GEMM core ----------------
// Ring of 4 K-chunks (K=32 each). LDS per matrix: 4 x [256][32] f16 = 64 KB.
// Swizzle: LDS[row][blk'] holds global[row][blk' ^ ((row>>1)&3)] (involution).
// Stages issued 3 chunks ahead; vmcnt(8) at chunk end (never 0 mid-loop).

DEV void ld_lds16(const void* g, void* l) {
  __builtin_amdgcn_global_load_lds((const __attribute__((address_space(1))) void*)g,
                                   (__attribute__((address_space(3))) void*)l, 16, 0, 0);
}

template <int NC>
DEV void gemm_pipe(const u16* __restrict__ A, int lda, const u16* __restrict__ B, int ldb,
                   u16* As, u16* Bs, f32x4 (&acc)[8][4]) {
  static_assert(NC >= 4, "pipeline needs >=4 chunks");
  const int tid = threadIdx.x;
  const int lane = tid & 63, wid = tid >> 6;   // 8 waves
  const int wr = wid >> 2, wc = wid & 3;       // 2 (M) x 4 (N)

  // ---- stage addressing: instr j covers LDS rows wid*32 + j*16 + (lane>>2), blk' = lane&3
  const int r0 = wid * 32 + (lane >> 2);
  const int r1 = r0 + 16;
  const int cb0 = (lane & 3) ^ ((r0 >> 1) & 3);
  const int cb1 = (lane & 3) ^ ((r1 >> 1) & 3);
  const int ldsO0 = wid * 1024;        // u16 elements within 16KB slot
  const int ldsO1 = wid * 1024 + 512;
  const u16* gA0 = A + (size_t)r0 * lda + cb0 * 8;
  const u16* gA1 = A + (size_t)r1 * lda + cb1 * 8;
  const u16* gB0 = B + (size_t)r0 * ldb + cb0 * 8;
  const u16* gB1 = B + (size_t)r1 * ldb + cb1 * 8;

  // ---- ds_read byte offsets within a slot (swizzled)
  const int kb = lane >> 4;            // k-block 0..3
  int ar[8], br[4];
#pragma unroll
  for (int m = 0; m < 8; ++m) {
    const int R = wr * 128 + m * 16 + (lane & 15);
    ar[m] = R * 64 + ((kb ^ ((R >> 1) & 3)) * 16);
  }
#pragma unroll
  for (int n = 0; n < 4; ++n) {
    const int C = wc * 64 + n * 16 + (lane & 15);
    br[n] = C * 64 + ((kb ^ ((C >> 1) & 3)) * 16);
  }

  // ---- prologue: stage chunks 0,1,2
  {
    const u16 *a0 = gA0, *a1 = gA1, *b0 = gB0, *b1 = gB1;
#pragma unroll
    for (int c = 0; c < 3; ++c) {
      ld_lds16(a0, As + c * 8192 + ldsO0);
      ld_lds16(a1, As + c * 8192 + ldsO1);
      ld_lds16(b0, Bs + c * 8192 + ldsO0);
      ld_lds16(b1, Bs + c * 8192 + ldsO1);
      a0 += 32; a1 += 32; b0 += 32; b1 += 32;
    }
  }
  const u16 *sA0 = gA0 + 96, *sA1 = gA1 + 96, *sB0 = gB0 + 96, *sB1 = gB1 + 96;
  asm volatile("s_waitcnt vmcnt(8)" ::: "memory");   // chunk 0 landed; 1,2 in flight
  __builtin_amdgcn_s_barrier();

  for (int ch = 0; ch < NC; ++ch) {
    const char* Asl = (const char*)(As + (ch & 3) * 8192);
    const char* Bsl = (const char*)(Bs + (ch & 3) * 8192);
    const bool st = (ch + 3) < NC;
    const int ssl = (ch + 3) & 3;

    f16x8 av[8], bv0, bv1, bv2, bv3;
    // ---- phase alpha: A frags + B[0..1], stage A(ch+3)
#pragma unroll
    for (int m = 0; m < 8; ++m) av[m] = *(const f16x8*)(Asl + ar[m]);
    bv0 = *(const f16x8*)(Bsl + br[0]);
    bv1 = *(const f16x8*)(Bsl + br[1]);
    if (st) {
      ld_lds16(sA0, As + ssl * 8192 + ldsO0);
      ld_lds16(sA1, As + ssl * 8192 + ldsO1);
    }
    __builtin_amdgcn_s_barrier();
    asm volatile("s_waitcnt lgkmcnt(0)" ::: "memory");
    __builtin_amdgcn_s_setprio(1);
#pragma unroll
    for (int m = 0; m < 8; ++m) {
      acc[m][0] = MFMA16(av[m], bv0, acc[m][0], 0, 0, 0);
      acc[m][1] = MFMA16(av[m], bv1, acc[m][1], 0, 0, 0);
    }
    __builtin_amdgcn_s_setprio(0);
    __builtin_amdgcn_s_barrier();

    // ---- phase beta: B[2..3], stage B(ch+3)
    bv2 = *(const f16x8*)(Bsl + br[2]);
    bv3 = *(const f16x8*)(Bsl + br[3]);
    if (st) {
      ld_lds16(sB0, Bs + ssl * 8192 + ldsO0);
      ld_lds16(sB1, Bs + ssl * 8192 + ldsO1);
    }
    __builtin_amdgcn_s_barrier();
    asm volatile("s_waitcnt lgkmcnt(0)" ::: "memory");
    __builtin_amdgcn_s_setprio(1);
#pragma unroll
    for (int m = 0; m < 8; ++m) {
      acc[m][2] = MFMA16(av[m], bv2, acc[m][2], 0, 0, 0);
      acc[m][3] = MFMA16(av[m], bv3, acc[m][3], 0, 0, 0);
    }
    __builtin_amdgcn_s_setprio(0);
    sA0 += 32; sA1 += 32; sB0 += 32; sB1 += 32;

    // ---- end of chunk: ensure ch+1 landed, keep rest in flight
    if (ch < NC - 3)       asm volatile("s_waitcnt vmcnt(8)" ::: "memory");
    else if (ch == NC - 3) asm volatile("s_waitcnt vmcnt(4)" ::: "memory");
    else if (ch == NC - 2) asm volatile("s_waitcnt vmcnt(0)" ::: "memory");
    __builtin_amdgcn_s_barrier();
  }
}

// GEMM1: h[b] = gate * gelu(x[b] @ W1^T + b1)   M=2048 N=2048 K=512 per sample
template <int BANK>
__global__ __launch_bounds__(512, 2) void k_ffn1(
    const u16* __restrict__ xh, const u16* __restrict__ w1, const float* __restrict__ b1,
    const int* __restrict__ idx, const float* __restrict__ gate, u16* __restrict__ h) {
  __shared__ alignas(16) u16 As[4 * 8192];
  __shared__ alignas(16) u16 Bs[4 * 8192];
  int wg = blockIdx.x;
  const int q = (int)gridDim.x >> 3;                 // 1024/8 = 128
  wg = (wg & 7) * q + (wg >> 3);                     // XCD-contiguous tiles
  const int b  = wg >> 6;
  const int mt = (wg >> 3) & 7;
  const int nt = wg & 7;

  const int e   = (BANK == 0) ? 0 : idx[(BANK - 1) * 16 + b];
  const float g = (BANK == 0) ? 1.0f : gate[(BANK - 1) * 16 + b];
  const u16* Ab = xh + ((size_t)b * T + (size_t)mt * 256) * D;
  const u16* Bb = w1 + (size_t)e * DFF * D + (size_t)nt * 256 * D;
  const float* bb = b1 + (size_t)e * DFF;

  f32x4 acc[8][4];
#pragma unroll
  for (int m = 0; m < 8; ++m)
#pragma unroll
    for (int n = 0; n < 4; ++n)
#pragma unroll
      for (int r = 0; r < 4; ++r) acc[m][n][r] = 0.f;

  gemm_pipe<16>(Ab, D, Bb, D, As, Bs, acc);

  const int lane = threadIdx.x & 63, wid = threadIdx.x >> 6;
  const int wr = wid >> 2, wc = wid & 3;
  const int rr = (lane >> 4) << 2, cc = lane & 15;
  const int mrow = mt * 256 + wr * 128;
  const int ncol = nt * 256 + wc * 64;
  u16* hb = h + (size_t)b * T * DFF;
  float bias[4];
#pragma unroll
  for (int n = 0; n < 4; ++n) bias[n] = bb[ncol + n * 16 + cc];
#pragma unroll
  for (int m = 0; m < 8; ++m) {
    const int row = mrow + m * 16 + rr;
#pragma unroll
    for (int n = 0; n < 4; ++n) {
      const int col = ncol + n * 16 + cc;
      const f32x4 a = acc[m][n];
#pragma unroll
      for (int r = 0; r < 4; ++r) {
        const float v = gelu_fast(a[r] + bias[n]) * g;
        hb[(size_t)(row + r) * DFF + col] = f2h(v);
      }
    }
  }
}

// GEMM2: out[b] (+)= h[b] @ W2^T (+ bias_total on BANK 0)   M=2048 N=512 K=2048
template <int BANK>
__global__ __launch_bounds__(512, 2) void k_ffn2(
    const u16* __restrict__ h, const u16* __restrict__ w2, const float* __restrict__ btot,
    const int* __restrict__ idx, float* __restrict__ out) {
  __shared__ alignas(16) u16 As[4 * 8192];
  __shared__ alignas(16) u16 Bs[4 * 8192];
  int wg = blockIdx.x;
  const int q = (int)gridDim.x >> 3;                 // 256/8 = 32
  wg = (wg & 7) * q + (wg >> 3);
  const int b  = wg >> 4;
  const int mt = (wg >> 1) & 7;
  const int nt = wg & 1;

  const int e = (BANK == 0) ? 0 : idx[(BANK - 1) * 16 + b];
  const u16* Ab = h + ((size_t)b * T + (size_t)mt * 256) * DFF;
  const u16* Bb = w2 + (size_t)e * D * DFF + (size_t)nt * 256 * DFF;

  f32x4 acc[8][4];
#pragma unroll
  for (int m = 0; m < 8; ++m)
#pragma unroll
    for (int n = 0; n < 4; ++n)
#pragma unroll
      for (int r = 0; r < 4; ++r) acc[m][n][r] = 0.f;

  gemm_pipe<64>(Ab, DFF, Bb, DFF, As, Bs, acc);

  const int lane = threadIdx.x & 63, wid = threadIdx.x >> 6;
  const int wr = wid >> 2, wc = wid & 3;
  const int rr = (lane >> 4) << 2, cc = lane & 15;
  const int mrow = mt * 256 + wr * 128;
  const int ncol = nt * 256 + wc * 64;
  float* ob = out + (size_t)b * T * D;
  float bt[4];
#pragma unroll
  for (int n = 0; n < 4; ++n) bt[n] = btot[b * D + ncol + n * 16 + cc];
#pragma unroll
  for (int m = 0; m < 8; ++m) {
    const int row = mrow + m * 16 + rr;
#pragma unroll
    for (int n = 0; n < 4; ++n) {
      const int col = ncol + n * 16 + cc;
      const f32x4 a = acc[m][n];
#pragma unroll
      for (int r = 0; r < 4; ++r) {
        const size_t oi = (size_t)(row + r) * D + col;
        if (BANK == 0) ob[oi] = a[r] + bt[n];
        else           ob[oi] += a[r];
      }
    }
  }
}

// ---------------- launch ----------------

extern "C" void kernel_launch(void* const* d_in, const int* in_sizes, int n_in,
                              void* d_out, int out_size, void* d_ws, size_t ws_size,
                              hipStream_t stream) {
  (void)in_sizes; (void)n_in; (void)out_size; (void)ws_size;
  const float* x    = (const float*)d_in[0];
  const float* base = (const float*)d_in[1];
  const float* attn = (const float*)d_in[2];
  const float* sw1  = (const float*)d_in[3];
  const float* sb1  = (const float*)d_in[4];
  const float* sw2  = (const float*)d_in[5];
  const float* sb2  = (const float*)d_in[6];
  const float* arw  = (const float*)d_in[7];
  const float* arb  = (const float*)d_in[8];
  const float* erw  = (const float*)d_in[9];
  const float* erb  = (const float*)d_in[10];
  const float* aw1  = (const float*)d_in[11];
  const float* ab1  = (const float*)d_in[12];
  const float* aw2  = (const float*)d_in[13];
  const float* ab2  = (const float*)d_in[14];
  const float* ew1  = (const float*)d_in[15];
  const float* eb1  = (const float*)d_in[16];
  const float* ew2  = (const float*)d_in[17];
  const float* eb2  = (const float*)d_in[18];
  float* out = (float*)d_out;

  char* w = (char*)d_ws;
  u16* xh   = (u16*)w;  w += (size_t)NB * T * D * 2;
  u16* hbuf = (u16*)w;  w += (size_t)NB * T * DFF * 2;
  u16* w1s  = (u16*)w;  w += (size_t)DFF * D * 2;
  u16* w2s  = (u16*)w;  w += (size_t)D * DFF * 2;
  u16* w1a  = (u16*)w;  w += (size_t)NE * DFF * D * 2;
  u16* w2a  = (u16*)w;  w += (size_t)NE * D * DFF * 2;
  u16* w1e  = (u16*)w;  w += (size_t)NE * DFF * D * 2;
  u16* w2e  = (u16*)w;  w += (size_t)NE * D * DFF * 2;
  float* part = (float*)w; w += (size_t)2 * NB * 16 * D * 4;
  float* feat = (float*)w; w += (size_t)NB * FEAT * 4;
  int*   idx  = (int*)w;   w += 32 * 4;
  float* gate = (float*)w; w += 32 * 4;
  float* btot = (float*)w; w += (size_t)NB * D * 4;

  // routing path
  k_part<<<dim3(256), dim3(512), 0, stream>>>(base, attn, part);
  k_feat<<<dim3(16), dim3(512), 0, stream>>>(part, feat);
  k_route<<<dim3(32), dim3(64), 0, stream>>>(feat, arw, arb, erw, erb, idx, gate);
  k_btot<<<dim3(16), dim3(512), 0, stream>>>(sb2, ab2, eb2, idx, gate, btot);

  // fp32 -> fp16 casts
  {
    long n;
    n = (long)NB * T * D;      k_cast<<<(unsigned)(n / 1024), 256, 0, stream>>>(x,   xh,  n);
    n = (long)DFF * D;         k_cast<<<(unsigned)(n / 1024), 256, 0, stream>>>(sw1, w1s, n);
    n = (long)D * DFF;         k_cast<<<(unsigned)(n / 1024), 256, 0, stream>>>(sw2, w2s, n);
    n = (long)NE * DFF * D;    k_cast<<<(unsigned)(n / 1024), 256, 0, stream>>>(aw1, w1a, n);
    n = (long)NE * D * DFF;    k_cast<<<(unsigned)(n / 1024), 256, 0, stream>>>(aw2, w2a, n);
    n = (long)NE * DFF * D;    k_cast<<<(unsigned)(n / 1024), 256, 0, stream>>>(ew1, w1e, n);
    n = (long)NE * D * DFF;    k_cast<<<(unsigned)(n / 1024), 256, 0, stream>>>(ew2, w2e, n);
  }

  // three bank passes (stream-serialized: ffn2<k> reads hbuf written by ffn1<k>)
  const dim3 g1(1024), g2(256), blk(512);
  k_ffn1<0><<<g1, blk, 0, stream>>>(xh, w1s, sb1, idx, gate, hbuf);
  k_ffn2<0><<<g2, blk, 0, stream>>>(hbuf, w2s, btot, idx, out);
  k_ffn1<1><<<g1, blk, 0, stream>>>(xh, w1a, ab1, idx, gate, hbuf);
  k_ffn2<1><<<g2, blk, 0, stream>>>(hbuf, w2a, btot, idx, out);
  k_ffn1<2><<<g1, blk, 0, stream>>>(xh, w1e, eb1, idx, gate, hbuf);
  k_ffn2<2><<<g2, blk, 0, stream>>>(hbuf, w2e, btot, idx, out);
}